// Round 17
// baseline (524.050 us; speedup 1.0000x reference)
//
#include <hip/hip_runtime.h>
#include <cstdint>

typedef unsigned int uint;
typedef unsigned short ushort;

typedef __attribute__((ext_vector_type(8))) short short8;
typedef __attribute__((ext_vector_type(4))) float f32x4;

// ---------- helpers ----------
__device__ inline uint f2bf(float x){ uint u = __builtin_bit_cast(uint, x); return (u + 0x7fffu + ((u>>16)&1u)) >> 16; }
__device__ inline float bflo(uint u){ return __builtin_bit_cast(float, u<<16); }
__device__ inline float bfhi(uint u){ return __builtin_bit_cast(float, u & 0xffff0000u); }
__device__ inline float bf2f(ushort u){ return __builtin_bit_cast(float, ((uint)u)<<16); }

typedef _Float16 h2_t __attribute__((ext_vector_type(2)));
__device__ inline h2_t u2h2(uint u){ return __builtin_bit_cast(h2_t, u); }
__device__ inline uint pack_h2(float a, float b){ h2_t h; h[0] = (_Float16)a; h[1] = (_Float16)b; return __builtin_bit_cast(uint, h); }
__device__ inline ushort f16bits(float x){ _Float16 h = (_Float16)x; return __builtin_bit_cast(ushort, h); }

#ifndef __has_builtin
#define __has_builtin(x) 0
#endif
#if __has_builtin(__builtin_amdgcn_fdot2)
__device__ inline float fdot2(uint hp, uint wp, float c){ return __builtin_amdgcn_fdot2(u2h2(hp), u2h2(wp), c, false); }
#else
__device__ inline float fdot2(uint hp, uint wp, float c){ h2_t a=u2h2(hp), b=u2h2(wp); return c + (float)a[0]*(float)b[0] + (float)a[1]*(float)b[1]; }
#endif

__device__ inline float sigm(float x){ return 1.f/(1.f + __expf(-x)); }
__device__ inline float tanh_(float x){ float e = __expf(-2.f*fabsf(x)); float t = (1.f-e)/(1.f+e); return copysignf(t, x); }

__device__ inline f32x4 mfma16(short8 a, short8 b, f32x4 c){
  return __builtin_amdgcn_mfma_f32_16x16x32_bf16(a, b, c, 0, 0, 0);
}

// ---------- prep1 ----------
// Tiled transpose [64 o][Ksrc k] f32 -> [k][64 o] bf16, tile = 100 k
__device__ void transpose_tile(const float* __restrict__ src, ushort* __restrict__ dst,
                               int Ksrc, int kbase, int tid)
{
  __shared__ float tl[64*101];
  for (int i = tid; i < 64*25; i += 256) {
    int c = i % 25, o = i / 25;
    float4 v = *(const float4*)(src + (long)o*Ksrc + kbase + c*4);
    float* lp = tl + o*101 + c*4;
    lp[0]=v.x; lp[1]=v.y; lp[2]=v.z; lp[3]=v.w;
  }
  __syncthreads();
  for (int i = tid; i < 100*64; i += 256) {
    int k = i >> 6, o = i & 63;
    dst[(long)(kbase + k)*64 + o] = (ushort)f2bf(tl[o*101 + k]);
  }
}

__global__ void prep_kernel(
  const float* __restrict__ adj, const float* __restrict__ g1w, const float* __restrict__ g2w,
  const float* __restrict__ lbw_i, const float* __restrict__ lbw_h,
  const float* __restrict__ lbb_i, const float* __restrict__ lbb_h,
  const float* __restrict__ lmw_h,
  const float* __restrict__ fo1w, const float* __restrict__ fo1b,
  const float* __restrict__ fo2w, const float* __restrict__ fo2b,
  const float* __restrict__ low_i, const float* __restrict__ lob_i, const float* __restrict__ lob_h,
  const float* __restrict__ fm1w, const float* __restrict__ fm1b,
  const float* __restrict__ fm2w, const float* __restrict__ fm2b,
  const float* __restrict__ fb3w, const float* __restrict__ fo3w, const float* __restrict__ fm3w,
  float* __restrict__ bias_bg, float* __restrict__ WemT, float* __restrict__ be_m,
  float* __restrict__ WcoT, float* __restrict__ bias_og,
  ushort* __restrict__ fb3wT, ushort* __restrict__ fo3wT, ushort* __restrict__ fm3wT,
  uint* __restrict__ whhB, uint* __restrict__ whhM,
  ushort* __restrict__ adjfragG, ushort* __restrict__ w1fragG, ushort* __restrict__ g2fragG,
  ushort* __restrict__ Gbfrag)
{
  int bid = blockIdx.x, tid = threadIdx.x;
  if (bid < 324) {                                 // fb3wT
    transpose_tile(fb3w, fb3wT, 32400, bid*100, tid);
  } else if (bid < 648) {                          // fm3wT
    transpose_tile(fm3w, fm3wT, 32400, (bid-324)*100, tid);
  } else if (bid < 712) {                          // fo3wT
    transpose_tile(fo3w, fo3wT, 6400, (bid-648)*100, tid);
  } else if (bid < 728) {                          // Gbfrag [6 kc][42 ft][64][8] from lbw_i
    for (int i = (bid-712)*256 + tid; i < 6*42*512; i += 16*256) {
      int fr = i >> 9; int lane = (i >> 3) & 63; int j = i & 7;
      int kc = fr / 42, ft = fr - kc*42;
      int n = ft*16 + (lane & 15);
      int k = kc*32 + (lane >> 4)*8 + j;
      float v = (n < 648 && k < 162) ? lbw_i[n*162 + k] : 0.f;
      Gbfrag[i] = (ushort)f2bf(v);
    }
  } else if (bid == 728) {                         // bias_bg, be_m
    for (int g = tid; g < 672; g += 256)
      bias_bg[g] = (g<648) ? lbb_i[g]+lbb_h[g] : 0.f;
    for (int n = tid; n < 192; n += 256) {
      float a = 0.f;
      if (n < 162) { for (int q=0;q<128;++q) a += fm2w[n*128+q]*fm1b[q]; a += fm2b[n]; }
      be_m[n] = a;
    }
  } else if (bid < 737) {                          // WemT [320][192]
    for (int idx = (bid-729)*256 + tid; idx < 320*192; idx += 8*256) {
      int ke = idx / 192, n = idx - ke*192;
      float a = 0.f;
      if (n < 162) for (int q=0;q<128;++q) a += fm2w[n*128+q]*fm1w[q*320+ke];
      WemT[idx] = a;
    }
  } else if (bid == 737) {                         // order collapse -> WcoT [32][128], bias_og
    __shared__ float sWo[1024];
    __shared__ float s_bo[32];
    for (int idx = tid; idx < 1024; idx += 256) {
      int j2 = idx >> 5, k2 = idx & 31;
      float a = 0.f;
      for (int q=0;q<128;++q) a += fo2w[j2*128+q]*fo1w[q*32+k2];
      sWo[idx] = a;
    }
    if (tid < 32) {
      float a = 0.f;
      for (int q=0;q<128;++q) a += fo2w[tid*128+q]*fo1b[q];
      s_bo[tid] = a + fo2b[tid];
    }
    __syncthreads();
    for (int idx = tid; idx < 4096; idx += 256) {
      int k2 = idx >> 7, n = idx & 127;
      float a = 0.f;
      for (int j2=0;j2<32;++j2) a += low_i[n*32+j2]*sWo[j2*32+k2];
      WcoT[idx] = a;
    }
    if (tid < 128) {
      int n = tid;
      float a = lob_i[n] + lob_h[n];
      for (int j2=0;j2<32;++j2) a += low_i[n*32+j2]*s_bo[j2];
      bias_og[n] = a;
    }
  } else if (bid < 746) {                          // whhB f16 pack [4][768][21]
    for (int idx = (bid-738)*256 + tid; idx < 4*768*21; idx += 8*256) {
      int kh = idx / (768*21); int rem = idx - kh*(768*21);
      int g = rem / 21, q = rem - g*21;
      int p = kh*21 + q; int k0 = 2*p;
      float e0=0.f, e1=0.f;
      if (g < 648) {
        if (k0 < 162)   e0 = lbw_h[g*162 + k0];
        if (k0+1 < 162) e1 = lbw_h[g*162 + k0 + 1];
      }
      whhB[idx] = pack_h2(e0, e1);
    }
  } else if (bid < 754) {                          // whhM f16 pack [4][768][21]
    for (int idx = (bid-746)*256 + tid; idx < 4*768*21; idx += 8*256) {
      int kh = idx / (768*21); int rem = idx - kh*(768*21);
      int g = rem / 21, q = rem - g*21;
      int p = kh*21 + q; int k0 = 2*p;
      float e0=0.f, e1=0.f;
      if (g < 648) {
        if (k0 < 162)   e0 = lmw_h[g*162 + k0];
        if (k0+1 < 162) e1 = lmw_h[g*162 + k0 + 1];
      }
      whhM[idx] = pack_h2(e0, e1);
    }
  } else if (bid == 754) {                         // MFMA frag packs for gcn2
    for (int idx = tid; idx < 18*64*8; idx += 256) {
      int fr = idx >> 9; int lane = (idx >> 3) & 63; int j = idx & 7;
      int lt = fr / 3, kc = fr - lt*3;
      int l = lt*16 + (lane & 15);
      int m = kc*32 + (lane >> 4)*8 + j;
      float v = (l < 81 && m < 81) ? adj[l*81 + m] : 0.f;
      adjfragG[idx] = (ushort)f2bf(v);
    }
    for (int idx = tid; idx < 2*64*8; idx += 256) {
      int ft = idx >> 9; int lane = (idx>>3)&63; int j = idx&7;
      int ff = 16*ft + (lane&15); int k = (lane>>4)*8 + j;
      w1fragG[idx] = (ushort)f2bf(g1w[ff*32 + k]);
    }
    for (int idx = tid; idx < 64*8; idx += 256) {
      int lane = idx>>3; int j = idx&7;
      int c = lane&15; int ff = (lane>>4)*8 + j;
      g2fragG[idx] = (c < 2) ? (ushort)f2bf(g2w[c*32 + ff]) : (ushort)0;
    }
  }
}

// ---------- prep2: msg-path full collapse ----------
__global__ void prep2_kernel(
  const float* __restrict__ lmw_i, const float* __restrict__ lmb_i, const float* __restrict__ lmb_h,
  const float* __restrict__ WemT, const float* __restrict__ be_m, const float* __restrict__ WcoT,
  ushort* __restrict__ Wbigfrag, float* __restrict__ bias_mgbig, ushort* __restrict__ Wofrag)
{
  int bid = blockIdx.x, tid = threadIdx.x;
  if (bid < 420) {                                 // Wbigfrag [10 kc][42 ft][64][8]
    int kc = bid / 42, ft = bid - kc*42;
    for (int e = tid; e < 512; e += 256) {
      int lane = e >> 3, j = e & 7;
      int n = ft*16 + (lane & 15);
      int k = kc*32 + (lane >> 4)*8 + j;
      float a = 0.f;
      if (n < 648) {
        const float* lw = lmw_i + (long)n*162;
        const float* wm = WemT + (long)k*192;
        for (int d = 0; d < 162; ++d) a += lw[d] * wm[d];
      }
      Wbigfrag[((long)bid*64 + lane)*8 + j] = (ushort)f2bf(a);
    }
  } else if (bid == 420) {                         // bias_mgbig [672]
    for (int n = tid; n < 672; n += 256) {
      float a = 0.f;
      if (n < 648) {
        a = lmb_i[n] + lmb_h[n];
        const float* lw = lmw_i + (long)n*162;
        for (int d = 0; d < 162; ++d) a += lw[d] * be_m[d];
      }
      bias_mgbig[n] = a;
    }
  } else {                                         // Wofrag [1][8][64][8]
    for (int i = tid; i < 4096; i += 256) {
      int ft = i >> 9; int lane = (i >> 3) & 63; int j = i & 7;
      int n = ft*16 + (lane & 15);
      int k = (lane >> 4)*8 + j;
      Wofrag[i] = (ushort)f2bf(WcoT[k*128 + n]);
    }
  }
}

// ---------- fused MFMA GCN: 1 wave = 1 site; 2 sites/block ----------
__global__ __launch_bounds__(128) void gcn2_kernel(
  const float* __restrict__ board,
  const ushort* __restrict__ adjfragG, const ushort* __restrict__ w1fragG,
  const ushort* __restrict__ g2fragG,
  const float* __restrict__ g1b, const float* __restrict__ g2b,
  ushort* __restrict__ bfout)   // bf16 [16000][192], cols 162..191 zero
{
  __shared__ ushort sX[2][3240];
  __shared__ ushort sF[2][3072];
  int tid = threadIdx.x; int w = tid >> 6; int lane = tid & 63;
  int col = lane & 15, grp = lane >> 4;
  long site = (long)blockIdx.x*2 + w;
  ushort* X = sX[w]; ushort* F = sF[w];

  short8 adjf[6][3];
  #pragma unroll
  for (int lt = 0; lt < 6; ++lt)
    #pragma unroll
    for (int kc = 0; kc < 3; ++kc)
      adjf[lt][kc] = *(const short8*)(adjfragG + ((lt*3+kc)*64 + lane)*8);
  short8 w1f0 = *(const short8*)(w1fragG + lane*8);
  short8 w1f1 = *(const short8*)(w1fragG + (64 + lane)*8);
  short8 g2f  = *(const short8*)(g2fragG + lane*8);
  float b1lo = g1b[col], b1hi = g1b[col + 16];
  float gb2  = (col < 2) ? g2b[col] : 0.f;
  f32x4 zero4 = {0.f, 0.f, 0.f, 0.f};
  short8 z8 = {0,0,0,0,0,0,0,0};

  const float* bp = board + site*2592;
  for (int idx = lane; idx < 648; idx += 64) {
    float4 v = *(const float4*)(bp + idx*4);
    uint lo = (f2bf(v.y)<<16) | f2bf(v.x);
    uint hi = (f2bf(v.w)<<16) | f2bf(v.z);
    int m = idx >> 3, q = idx & 7;
    *(uint2*)((char*)X + m*80 + q*8) = make_uint2(lo, hi);
  }
  if (grp >= 2) {
    *(short8*)((char*)F + (2*64 + lane)*16)     = z8;
    *(short8*)((char*)F + ((3+2)*64 + lane)*16) = z8;
  }

  #pragma unroll
  for (int lt = 0; lt < 6; ++lt) {
    short8 a = *(const short8*)((char*)X + (lt*16 + col)*80 + grp*16);
    f32x4 a0 = mfma16(a, w1f0, zero4);
    f32x4 a1 = mfma16(a, w1f1, zero4);
    #pragma unroll
    for (int r = 0; r < 4; ++r) {
      int m = lt*16 + grp*4 + r;
      if (m < 81) {
        int kc = m >> 5, g8 = (m & 31) >> 3, j = m & 7;
        ((ushort*)F)[ (kc*64 + g8*16 + col)*8 + j ]     = (ushort)f2bf(a0[r] + b1lo);
        ((ushort*)F)[ ((3+kc)*64 + g8*16 + col)*8 + j ] = (ushort)f2bf(a1[r] + b1hi);
      }
    }
  }

  short8 t1[2][3];
  #pragma unroll
  for (int ft = 0; ft < 2; ++ft)
    #pragma unroll
    for (int kc = 0; kc < 3; ++kc)
      t1[ft][kc] = *(const short8*)((char*)F + ((ft*3+kc)*64 + lane)*16);
  #pragma unroll
  for (int lt = 0; lt < 6; ++lt) {
    f32x4 c0 = zero4, c1 = zero4;
    #pragma unroll
    for (int kc = 0; kc < 3; ++kc) {
      c0 = mfma16(adjf[lt][kc], t1[0][kc], c0);
      c1 = mfma16(adjf[lt][kc], t1[1][kc], c1);
    }
    #pragma unroll
    for (int r = 0; r < 4; ++r) {
      int l = lt*16 + grp*4 + r;
      if (l < 81) {
        ((ushort*)X)[ l*40 + col ]      = (ushort)f2bf(fmaxf(c0[r], 0.f));
        ((ushort*)X)[ l*40 + col + 16 ] = (ushort)f2bf(fmaxf(c1[r], 0.f));
      }
    }
  }

  if (grp >= 2) *(short8*)((char*)F + (2*64 + lane)*16) = z8;

  #pragma unroll
  for (int lt = 0; lt < 6; ++lt) {
    short8 h = *(const short8*)((char*)X + (lt*16 + col)*80 + grp*16);
    f32x4 d = mfma16(h, g2f, zero4);
    if (col < 2) {
      #pragma unroll
      for (int r = 0; r < 4; ++r) {
        int m = lt*16 + grp*4 + r;
        if (m < 81) {
          int kc = m >> 5, g8 = (m & 31) >> 3, j = m & 7;
          ((ushort*)F)[ (kc*64 + g8*16 + col)*8 + j ] = (ushort)f2bf(d[r] + gb2);
        }
      }
    }
  }

  short8 t2[3];
  #pragma unroll
  for (int kc = 0; kc < 3; ++kc)
    t2[kc] = *(const short8*)((char*)F + (kc*64 + lane)*16);
  ushort* bfu = bfout + site*192;
  if (lane < 15) ((uint*)bfu)[81 + lane] = 0;   // zero pad cols 162..191
  #pragma unroll
  for (int lt = 0; lt < 6; ++lt) {
    f32x4 e = zero4;
    #pragma unroll
    for (int kc = 0; kc < 3; ++kc)
      e = mfma16(adjf[lt][kc], t2[kc], e);
    if (col < 2) {
      #pragma unroll
      for (int r = 0; r < 4; ++r) {
        int l = lt*16 + grp*4 + r;
        if (l < 81) bfu[l*2 + col] = (ushort)f2bf(fmaxf(e[r], 0.f));
      }
    }
  }
}

// ---------- MFMA GEMM: n-groups split across gridDim.y for occupancy ----------
template<int KC, int NT, int SRC_F32, int K, int NVALID, int OSTRIDE>
__global__ __launch_bounds__(512) void mgemm_kernel(
    const void* __restrict__ Ain, const ushort* __restrict__ Bfrag,
    const float* __restrict__ bias, ushort* __restrict__ out)
{
  constexpr int LSTRIDE = KC*64 + 16;
  __shared__ __align__(16) char sA[64 * LSTRIDE];
  int tid = threadIdx.x; int w = tid >> 6, lane = tid & 63;
  int col = lane & 15, grp = lane >> 4;
  long rowbase = (long)blockIdx.x * 64;
  int ystart = blockIdx.y * 8;
  int ystride = gridDim.y * 8;

  if (SRC_F32) {
    constexpr int CH = K/8;
    const float* Af = (const float*)Ain + rowbase*K;
    for (int i = tid; i < 64*CH; i += 512) {
      int ch = i % CH, r = i / CH;
      const float* sp = Af + (long)r*K + ch*8;
      float4 v0 = *(const float4*)sp, v1 = *(const float4*)(sp+4);
      uint4 u;
      u.x = (f2bf(v0.y)<<16) | f2bf(v0.x);
      u.y = (f2bf(v0.w)<<16) | f2bf(v0.z);
      u.z = (f2bf(v1.y)<<16) | f2bf(v1.x);
      u.w = (f2bf(v1.w)<<16) | f2bf(v1.z);
      *(uint4*)(sA + r*LSTRIDE + ch*16) = u;
    }
  } else {
    constexpr int CH = KC*4;
    const ushort* Ab = (const ushort*)Ain + rowbase*(KC*32);
    for (int i = tid; i < 64*CH; i += 512) {
      int ch = i % CH, r = i / CH;
      *(uint4*)(sA + r*LSTRIDE + ch*16) = *(const uint4*)(Ab + (long)r*(KC*32) + ch*8);
    }
  }
  __syncthreads();

  constexpr int NG = NT/2;
  for (int ng = w + ystart; ng < NG; ng += ystride) {
    int nt0 = ng*2;
    float bi0 = bias[nt0*16 + col], bi1 = bias[nt0*16 + 16 + col];
    f32x4 acc[4][2];
    #pragma unroll
    for (int mt=0;mt<4;++mt){
      acc[mt][0] = f32x4{bi0,bi0,bi0,bi0};
      acc[mt][1] = f32x4{bi1,bi1,bi1,bi1};
    }
    #pragma unroll 2
    for (int kc=0; kc<KC; ++kc) {
      const ushort* bp = Bfrag + (((long)kc*NT + nt0)*64 + lane)*8;
      short8 b0 = *(const short8*)bp;
      short8 b1 = *(const short8*)(bp + 512);
      #pragma unroll
      for (int mt=0; mt<4; ++mt) {
        short8 a = *(const short8*)(sA + (mt*16+col)*LSTRIDE + kc*64 + grp*16);
        acc[mt][0] = mfma16(a, b0, acc[mt][0]);
        acc[mt][1] = mfma16(a, b1, acc[mt][1]);
      }
    }
    #pragma unroll
    for (int mt=0;mt<4;++mt){
      #pragma unroll
      for (int nt=0;nt<2;++nt){
        int cg = nt0*16 + nt*16 + col;
        if (cg < NVALID) {
          #pragma unroll
          for (int r=0;r<4;++r){
            long row = rowbase + mt*16 + grp*4 + r;
            out[row*OSTRIDE + cg] = (ushort)f2bf(acc[mt][nt][r]);
          }
        }
      }
    }
  }
}

// ---------- LSTM recurrence: R3 design (banked best: 205 us) ----------
__global__ __launch_bounds__(1024) void lstm_kernel(
  const ushort* __restrict__ Gb, const ushort* __restrict__ Gm, const ushort* __restrict__ Go,
  const uint* __restrict__ whhB, const uint* __restrict__ whhM,
  const float* __restrict__ low_h,
  ushort* __restrict__ hsb, ushort* __restrict__ hsm, ushort* __restrict__ hso)
{
  int bid = blockIdx.x, tid = threadIdx.x;
  int f = bid / 80; int rr = bid - f*80;
  int pp = rr >> 4, jj = rr & 15;
  __shared__ __align__(16) uint s_h[96];
  __shared__ float s_part[4][784];
  if (f < 2) {
    const ushort* G  = f ? Gm : Gb;
    const uint* wh   = f ? whhM : whhB;
    ushort* hs       = f ? hsm : hsb;
    int kh = tid >> 8, g = tid & 255;
    uint w0[21], w1[21], w2[21];
    {
      const uint* wp = wh + (kh*768 + g)*21;
      #pragma unroll
      for (int q=0;q<21;++q){ w0[q]=wp[q]; w1[q]=wp[256*21+q]; w2[q]=wp[512*21+q]; }
    }
    if (tid < 96) s_h[tid] = 0u;
    float cc = 0.f;
    ushort pf0=0,pf1=0,pf2=0,pf3=0;
    if (tid < 162) {
      const ushort* Gr = G + (long)(pp*200 + jj)*648;
      pf0=Gr[tid]; pf1=Gr[162+tid]; pf2=Gr[324+tid]; pf3=Gr[486+tid];
    }
    __syncthreads();
    for (int t = 0; t < 200; ++t) {
      float a0=0.f, a1=0.f, a2=0.f;
      const uint* hb = s_h + kh*24;
      #pragma unroll
      for (int q4=0; q4<5; ++q4) {
        uint4 hv = *(const uint4*)(hb + q4*4);
        int q = q4*4;
        a0=fdot2(hv.x,w0[q  ],a0); a1=fdot2(hv.x,w1[q  ],a1); a2=fdot2(hv.x,w2[q  ],a2);
        a0=fdot2(hv.y,w0[q+1],a0); a1=fdot2(hv.y,w1[q+1],a1); a2=fdot2(hv.y,w2[q+1],a2);
        a0=fdot2(hv.z,w0[q+2],a0); a1=fdot2(hv.z,w1[q+2],a1); a2=fdot2(hv.z,w2[q+2],a2);
        a0=fdot2(hv.w,w0[q+3],a0); a1=fdot2(hv.w,w1[q+3],a1); a2=fdot2(hv.w,w2[q+3],a2);
      }
      { uint hv = hb[20];
        a0=fdot2(hv,w0[20],a0); a1=fdot2(hv,w1[20],a1); a2=fdot2(hv,w2[20],a2); }
      s_part[kh][g      ] = a0;
      s_part[kh][g + 256] = a1;
      s_part[kh][g + 512] = a2;
      __syncthreads();
      if (tid < 162) {
        float gi = s_part[0][tid    ]+s_part[1][tid    ]+s_part[2][tid    ]+s_part[3][tid    ] + bf2f(pf0);
        float gf = s_part[0][162+tid]+s_part[1][162+tid]+s_part[2][162+tid]+s_part[3][162+tid] + bf2f(pf1);
        float gg = s_part[0][324+tid]+s_part[1][324+tid]+s_part[2][324+tid]+s_part[3][324+tid] + bf2f(pf2);
        float go = s_part[0][486+tid]+s_part[1][486+tid]+s_part[2][486+tid]+s_part[3][486+tid] + bf2f(pf3);
        if (t+1 < 200) {
          int m2 = (t+1)*16 + jj; int bb = m2/200; int ss = m2 - bb*200;
          const ushort* Gr = G + (long)((bb*5+pp)*200 + ss)*648;
          pf0=Gr[tid]; pf1=Gr[162+tid]; pf2=Gr[324+tid]; pf3=Gr[486+tid];
        }
        cc = sigm(gf)*cc + sigm(gi)*tanh_(gg);
        float h = sigm(go)*tanh_(cc);
        int p = tid >> 1; int khw = p/21; int qw = p - khw*21;
        ((ushort*)s_h)[(khw*24+qw)*2 + (tid&1)] = f16bits(h);
        hs[(long)(t*80+rr)*162 + tid] = (ushort)f2bf(h);
      }
      __syncthreads();
    }
  } else {
    // order LSTM: H=32, 128 gates
    float w[32];
    if (tid < 128) {
      #pragma unroll
      for (int q=0;q<32;++q) w[q] = low_h[tid*32+q];
    }
    float* s_ho = (float*)s_h;          // 32 floats
    float* s_po = &s_part[0][0];        // 128 floats
    if (tid < 32) s_ho[tid] = 0.f;
    float cc=0.f; ushort pf0=0,pf1=0,pf2=0,pf3=0;
    if (tid < 32) {
      const ushort* Gr = Go + (long)(pp*200 + jj)*128;
      pf0=Gr[tid]; pf1=Gr[32+tid]; pf2=Gr[64+tid]; pf3=Gr[96+tid];
    }
    __syncthreads();
    for (int t=0; t<200; ++t) {
      if (tid < 128) {
        float a = 0.f;
        const float4* h4 = (const float4*)s_ho;
        #pragma unroll
        for (int q4=0;q4<8;++q4) {
          float4 hv = h4[q4];
          a += hv.x*w[q4*4] + hv.y*w[q4*4+1] + hv.z*w[q4*4+2] + hv.w*w[q4*4+3];
        }
        s_po[tid] = a;
      }
      __syncthreads();
      if (tid < 32) {
        float gi = s_po[tid]      + bf2f(pf0);
        float gf = s_po[32 + tid] + bf2f(pf1);
        float gg = s_po[64 + tid] + bf2f(pf2);
        float go = s_po[96 + tid] + bf2f(pf3);
        if (t+1 < 200) {
          int m2 = (t+1)*16 + jj; int bb = m2/200; int ss = m2 - bb*200;
          const ushort* Gr = Go + (long)((bb*5+pp)*200 + ss)*128;
          pf0=Gr[tid]; pf1=Gr[32+tid]; pf2=Gr[64+tid]; pf3=Gr[96+tid];
        }
        cc = sigm(gf)*cc + sigm(gi)*tanh_(gg);
        float h = sigm(go)*tanh_(cc);
        s_ho[tid] = h;
        hso[(long)(t*80+rr)*32 + tid] = (ushort)f2bf(h);
      }
      __syncthreads();
    }
  }
}

// ---------- final FC: K split 25-ways (t-groups of 8) for occupancy ----------
__global__ __launch_bounds__(256) void fc_kernel(
  const ushort* __restrict__ hsb, const ushort* __restrict__ hso, const ushort* __restrict__ hsm,
  const ushort* __restrict__ fb3wT, const ushort* __restrict__ fo3wT, const ushort* __restrict__ fm3wT,
  const float* __restrict__ fb3b, const float* __restrict__ fo3b, const float* __restrict__ fm3b,
  float* __restrict__ out)
{
  __shared__ float s_hsum[8*162];
  int bid = blockIdx.x, tid = threadIdx.x;
  int f = bid / 400;
  int rem = bid - f*400;
  int j = rem / 25, tg = rem - (rem/25)*25;
  int H = (f==1) ? 32 : 162;
  const ushort* hs = (f==0) ? hsb : (f==1) ? hso : hsm;
  const ushort* WT = (f==0) ? fb3wT : (f==1) ? fo3wT : fm3wT;
  int KL = 8*H;
  for (int idx = tid; idx < KL; idx += 256) {
    int tl = idx / H; int h = idx - tl*H;
    int t = tg*8 + tl;
    long base = (long)(t*80 + j)*H + h;
    float s = 0.f;
    #pragma unroll
    for (int p=0;p<5;++p) s += bf2f(hs[base + (long)p*16*H]);
    s_hsum[idx] = s;
  }
  __syncthreads();
  int o0 = (tid & 15)*4, kq = tid >> 4;
  float a0=0.f,a1=0.f,a2=0.f,a3=0.f;
  long kgbase = (long)tg*8*H;
  for (int kk = kq; kk < KL; kk += 16) {
    float hv = s_hsum[kk];
    const uint* wr = (const uint*)(WT + (kgbase + kk)*64 + o0);
    uint u0 = wr[0], u1 = wr[1];
    a0 += hv*bflo(u0); a1 += hv*bfhi(u0); a2 += hv*bflo(u1); a3 += hv*bfhi(u1);
  }
  __syncthreads();
  float* s_red = s_hsum;
  s_red[kq*64 + o0] = a0; s_red[kq*64 + o0 + 1] = a1;
  s_red[kq*64 + o0 + 2] = a2; s_red[kq*64 + o0 + 3] = a3;
  __syncthreads();
  if (tid < 64) {
    float v = 0.f;
    #pragma unroll
    for (int q=0;q<16;++q) v += s_red[q*64 + tid];
    if (f==0 && tg==0) v += 5.f*(fb3b[tid] + fo3b[tid] + fm3b[tid]);
    atomicAdd(out + j*64 + tid, v);
  }
}

// ---------- launch ----------
extern "C" void kernel_launch(void* const* d_in, const int* in_sizes, int n_in,
                              void* d_out, int out_size, void* d_ws, size_t ws_size,
                              hipStream_t stream)
{
  const float* board = (const float*)d_in[0];
  const float* order = (const float*)d_in[1];
  const float* msg   = (const float*)d_in[2];
  const float* adj   = (const float*)d_in[3];
  const float* g1w = (const float*)d_in[4];  const float* g1b = (const float*)d_in[5];
  const float* g2w = (const float*)d_in[6];  const float* g2b = (const float*)d_in[7];
  const float* lbw_i = (const float*)d_in[8];  const float* lbw_h = (const float*)d_in[9];
  const float* lbb_i = (const float*)d_in[10]; const float* lbb_h = (const float*)d_in[11];
  const float* fb3w = (const float*)d_in[12];  const float* fb3b = (const float*)d_in[13];
  const float* fo1w = (const float*)d_in[14];  const float* fo1b = (const float*)d_in[15];
  const float* fo2w = (const float*)d_in[16];  const float* fo2b = (const float*)d_in[17];
  const float* low_i = (const float*)d_in[18]; const float* low_h = (const float*)d_in[19];
  const float* lob_i = (const float*)d_in[20]; const float* lob_h = (const float*)d_in[21];
  const float* fo3w = (const float*)d_in[22];  const float* fo3b = (const float*)d_in[23];
  const float* fm1w = (const float*)d_in[24];  const float* fm1b = (const float*)d_in[25];
  const float* fm2w = (const float*)d_in[26];  const float* fm2b = (const float*)d_in[27];
  const float* lmw_i = (const float*)d_in[28]; const float* lmw_h = (const float*)d_in[29];
  const float* lmb_i = (const float*)d_in[30]; const float* lmb_h = (const float*)d_in[31];
  const float* fm3w = (const float*)d_in[32];  const float* fm3b = (const float*)d_in[33];

  char* wsb = (char*)d_ws;
  size_t off = 0;
  auto alloc = [&](size_t bytes)->char* { char* p = wsb + off; off = (off + bytes + 255) & ~(size_t)255; return p; };
  float* bias_bg   = (float*)alloc(672*4);
  float* WemT      = (float*)alloc((size_t)320*192*4);
  float* be_m      = (float*)alloc(192*4);
  float* WcoT      = (float*)alloc((size_t)32*128*4);
  float* bias_og   = (float*)alloc(128*4);
  float* bias_mgbig= (float*)alloc(672*4);
  ushort* fb3wT  = (ushort*)alloc((size_t)2073600*2);
  ushort* fo3wT  = (ushort*)alloc((size_t)409600*2);
  ushort* fm3wT  = (ushort*)alloc((size_t)2073600*2);
  uint* whhB     = (uint*)alloc((size_t)64512*4);
  uint* whhM     = (uint*)alloc((size_t)64512*4);
  ushort* adjfragG = (ushort*)alloc((size_t)18*64*8*2);
  ushort* w1fragG  = (ushort*)alloc((size_t)2*64*8*2);
  ushort* g2fragG  = (ushort*)alloc((size_t)64*8*2);
  ushort* Gbfrag   = (ushort*)alloc((size_t)6*42*512*2);
  ushort* Wbigfrag = (ushort*)alloc((size_t)10*42*512*2);
  ushort* Wofrag   = (ushort*)alloc((size_t)4096*2);
  ushort* bf     = (ushort*)alloc((size_t)16000*192*2);
  ushort* Gb     = (ushort*)alloc((size_t)16000*648*2);
  ushort* Gm     = (ushort*)alloc((size_t)16000*648*2);
  ushort* Go     = (ushort*)alloc((size_t)16000*128*2);
  ushort* hsb    = (ushort*)alloc((size_t)16000*162*2);
  ushort* hsm    = (ushort*)alloc((size_t)16000*162*2);
  ushort* hso    = (ushort*)alloc((size_t)16000*32*2);
  if (off > ws_size) return;

  prep_kernel<<<755, 256, 0, stream>>>(adj, g1w, g2w, lbw_i, lbw_h, lbb_i, lbb_h,
      lmw_h, fo1w, fo1b, fo2w, fo2b, low_i, lob_i, lob_h,
      fm1w, fm1b, fm2w, fm2b, fb3w, fo3w, fm3w,
      bias_bg, WemT, be_m, WcoT, bias_og,
      fb3wT, fo3wT, fm3wT, whhB, whhM, adjfragG, w1fragG, g2fragG, Gbfrag);
  prep2_kernel<<<422, 256, 0, stream>>>(lmw_i, lmb_i, lmb_h, WemT, be_m, WcoT,
      Wbigfrag, bias_mgbig, Wofrag);
  gcn2_kernel<<<8000, 128, 0, stream>>>(board, adjfragG, w1fragG, g2fragG, g1b, g2b, bf);
  mgemm_kernel<6,42,0,192,648,648><<<dim3(250,3), 512, 0, stream>>>(bf, Gbfrag, bias_bg, Gb);
  mgemm_kernel<10,42,1,320,648,648><<<dim3(250,3), 512, 0, stream>>>(msg, Wbigfrag, bias_mgbig, Gm);
  mgemm_kernel<1,8,1,32,128,128><<<250, 512, 0, stream>>>(order, Wofrag, bias_og, Go);
  lstm_kernel<<<240, 1024, 0, stream>>>(Gb, Gm, Go, whhB, whhM, low_h, hsb, hsm, hso);
  hipMemsetAsync(d_out, 0, (size_t)out_size*sizeof(float), stream);
  fc_kernel<<<1200, 256, 0, stream>>>(hsb, hso, hsm,
      fb3wT, fo3wT, fm3wT, fb3b, fo3b, fm3b, (float*)d_out);
}

// Round 18
// 514.695 us; speedup vs baseline: 1.0182x; 1.0182x over previous
//
#include <hip/hip_runtime.h>
#include <cstdint>

typedef unsigned int uint;
typedef unsigned short ushort;

typedef __attribute__((ext_vector_type(8))) short short8;
typedef __attribute__((ext_vector_type(4))) float f32x4;

// ---------- helpers ----------
__device__ inline uint f2bf(float x){ uint u = __builtin_bit_cast(uint, x); return (u + 0x7fffu + ((u>>16)&1u)) >> 16; }
__device__ inline float bflo(uint u){ return __builtin_bit_cast(float, u<<16); }
__device__ inline float bfhi(uint u){ return __builtin_bit_cast(float, u & 0xffff0000u); }
__device__ inline float bf2f(ushort u){ return __builtin_bit_cast(float, ((uint)u)<<16); }

typedef _Float16 h2_t __attribute__((ext_vector_type(2)));
__device__ inline h2_t u2h2(uint u){ return __builtin_bit_cast(h2_t, u); }
__device__ inline uint pack_h2(float a, float b){ h2_t h; h[0] = (_Float16)a; h[1] = (_Float16)b; return __builtin_bit_cast(uint, h); }
__device__ inline ushort f16bits(float x){ _Float16 h = (_Float16)x; return __builtin_bit_cast(ushort, h); }

#ifndef __has_builtin
#define __has_builtin(x) 0
#endif
#if __has_builtin(__builtin_amdgcn_fdot2)
__device__ inline float fdot2(uint hp, uint wp, float c){ return __builtin_amdgcn_fdot2(u2h2(hp), u2h2(wp), c, false); }
#else
__device__ inline float fdot2(uint hp, uint wp, float c){ h2_t a=u2h2(hp), b=u2h2(wp); return c + (float)a[0]*(float)b[0] + (float)a[1]*(float)b[1]; }
#endif

__device__ inline float sigm(float x){ return 1.f/(1.f + __expf(-x)); }
__device__ inline float tanh_(float x){ float e = __expf(-2.f*fabsf(x)); float t = (1.f-e)/(1.f+e); return copysignf(t, x); }

__device__ inline f32x4 mfma16(short8 a, short8 b, f32x4 c){
  return __builtin_amdgcn_mfma_f32_16x16x32_bf16(a, b, c, 0, 0, 0);
}

// ---------- prep1 ----------
// Tiled transpose [64 o][Ksrc k] f32 -> [k][64 o] bf16, tile = 100 k
__device__ void transpose_tile(const float* __restrict__ src, ushort* __restrict__ dst,
                               int Ksrc, int kbase, int tid)
{
  __shared__ float tl[64*101];
  for (int i = tid; i < 64*25; i += 256) {
    int c = i % 25, o = i / 25;
    float4 v = *(const float4*)(src + (long)o*Ksrc + kbase + c*4);
    float* lp = tl + o*101 + c*4;
    lp[0]=v.x; lp[1]=v.y; lp[2]=v.z; lp[3]=v.w;
  }
  __syncthreads();
  for (int i = tid; i < 100*64; i += 256) {
    int k = i >> 6, o = i & 63;
    dst[(long)(kbase + k)*64 + o] = (ushort)f2bf(tl[o*101 + k]);
  }
}

__global__ void prep_kernel(
  const float* __restrict__ adj, const float* __restrict__ g1w, const float* __restrict__ g2w,
  const float* __restrict__ lbw_i, const float* __restrict__ lbw_h,
  const float* __restrict__ lbb_i, const float* __restrict__ lbb_h,
  const float* __restrict__ lmw_h,
  const float* __restrict__ fo1w, const float* __restrict__ fo1b,
  const float* __restrict__ fo2w, const float* __restrict__ fo2b,
  const float* __restrict__ low_i, const float* __restrict__ lob_i, const float* __restrict__ lob_h,
  const float* __restrict__ fm1w, const float* __restrict__ fm1b,
  const float* __restrict__ fm2w, const float* __restrict__ fm2b,
  const float* __restrict__ fb3w, const float* __restrict__ fo3w, const float* __restrict__ fm3w,
  float* __restrict__ bias_bg, float* __restrict__ WemT, float* __restrict__ be_m,
  float* __restrict__ WcoT, float* __restrict__ bias_og,
  ushort* __restrict__ fb3wT, ushort* __restrict__ fo3wT, ushort* __restrict__ fm3wT,
  uint* __restrict__ whhB, uint* __restrict__ whhM,
  ushort* __restrict__ adjfragG, ushort* __restrict__ w1fragG, ushort* __restrict__ g2fragG,
  ushort* __restrict__ Gbfrag)
{
  int bid = blockIdx.x, tid = threadIdx.x;
  if (bid < 324) {                                 // fb3wT
    transpose_tile(fb3w, fb3wT, 32400, bid*100, tid);
  } else if (bid < 648) {                          // fm3wT
    transpose_tile(fm3w, fm3wT, 32400, (bid-324)*100, tid);
  } else if (bid < 712) {                          // fo3wT
    transpose_tile(fo3w, fo3wT, 6400, (bid-648)*100, tid);
  } else if (bid < 728) {                          // Gbfrag [6 kc][42 ft][64][8] from lbw_i
    for (int i = (bid-712)*256 + tid; i < 6*42*512; i += 16*256) {
      int fr = i >> 9; int lane = (i >> 3) & 63; int j = i & 7;
      int kc = fr / 42, ft = fr - kc*42;
      int n = ft*16 + (lane & 15);
      int k = kc*32 + (lane >> 4)*8 + j;
      float v = (n < 648 && k < 162) ? lbw_i[n*162 + k] : 0.f;
      Gbfrag[i] = (ushort)f2bf(v);
    }
  } else if (bid == 728) {                         // bias_bg, be_m
    for (int g = tid; g < 672; g += 256)
      bias_bg[g] = (g<648) ? lbb_i[g]+lbb_h[g] : 0.f;
    for (int n = tid; n < 192; n += 256) {
      float a = 0.f;
      if (n < 162) { for (int q=0;q<128;++q) a += fm2w[n*128+q]*fm1b[q]; a += fm2b[n]; }
      be_m[n] = a;
    }
  } else if (bid < 737) {                          // WemT [320][192]
    for (int idx = (bid-729)*256 + tid; idx < 320*192; idx += 8*256) {
      int ke = idx / 192, n = idx - ke*192;
      float a = 0.f;
      if (n < 162) for (int q=0;q<128;++q) a += fm2w[n*128+q]*fm1w[q*320+ke];
      WemT[idx] = a;
    }
  } else if (bid == 737) {                         // order collapse -> WcoT [32][128], bias_og
    __shared__ float sWo[1024];
    __shared__ float s_bo[32];
    for (int idx = tid; idx < 1024; idx += 256) {
      int j2 = idx >> 5, k2 = idx & 31;
      float a = 0.f;
      for (int q=0;q<128;++q) a += fo2w[j2*128+q]*fo1w[q*32+k2];
      sWo[idx] = a;
    }
    if (tid < 32) {
      float a = 0.f;
      for (int q=0;q<128;++q) a += fo2w[tid*128+q]*fo1b[q];
      s_bo[tid] = a + fo2b[tid];
    }
    __syncthreads();
    for (int idx = tid; idx < 4096; idx += 256) {
      int k2 = idx >> 7, n = idx & 127;
      float a = 0.f;
      for (int j2=0;j2<32;++j2) a += low_i[n*32+j2]*sWo[j2*32+k2];
      WcoT[idx] = a;
    }
    if (tid < 128) {
      int n = tid;
      float a = lob_i[n] + lob_h[n];
      for (int j2=0;j2<32;++j2) a += low_i[n*32+j2]*s_bo[j2];
      bias_og[n] = a;
    }
  } else if (bid < 746) {                          // whhB f16 pack [4][768][21]
    for (int idx = (bid-738)*256 + tid; idx < 4*768*21; idx += 8*256) {
      int kh = idx / (768*21); int rem = idx - kh*(768*21);
      int g = rem / 21, q = rem - g*21;
      int p = kh*21 + q; int k0 = 2*p;
      float e0=0.f, e1=0.f;
      if (g < 648) {
        if (k0 < 162)   e0 = lbw_h[g*162 + k0];
        if (k0+1 < 162) e1 = lbw_h[g*162 + k0 + 1];
      }
      whhB[idx] = pack_h2(e0, e1);
    }
  } else if (bid < 754) {                          // whhM f16 pack [4][768][21]
    for (int idx = (bid-746)*256 + tid; idx < 4*768*21; idx += 8*256) {
      int kh = idx / (768*21); int rem = idx - kh*(768*21);
      int g = rem / 21, q = rem - g*21;
      int p = kh*21 + q; int k0 = 2*p;
      float e0=0.f, e1=0.f;
      if (g < 648) {
        if (k0 < 162)   e0 = lmw_h[g*162 + k0];
        if (k0+1 < 162) e1 = lmw_h[g*162 + k0 + 1];
      }
      whhM[idx] = pack_h2(e0, e1);
    }
  } else if (bid == 754) {                         // MFMA frag packs for gcn2
    for (int idx = tid; idx < 18*64*8; idx += 256) {
      int fr = idx >> 9; int lane = (idx >> 3) & 63; int j = idx & 7;
      int lt = fr / 3, kc = fr - lt*3;
      int l = lt*16 + (lane & 15);
      int m = kc*32 + (lane >> 4)*8 + j;
      float v = (l < 81 && m < 81) ? adj[l*81 + m] : 0.f;
      adjfragG[idx] = (ushort)f2bf(v);
    }
    for (int idx = tid; idx < 2*64*8; idx += 256) {
      int ft = idx >> 9; int lane = (idx>>3)&63; int j = idx&7;
      int ff = 16*ft + (lane&15); int k = (lane>>4)*8 + j;
      w1fragG[idx] = (ushort)f2bf(g1w[ff*32 + k]);
    }
    for (int idx = tid; idx < 64*8; idx += 256) {
      int lane = idx>>3; int j = idx&7;
      int c = lane&15; int ff = (lane>>4)*8 + j;
      g2fragG[idx] = (c < 2) ? (ushort)f2bf(g2w[c*32 + ff]) : (ushort)0;
    }
  }
}

// ---------- prep2: msg-path full collapse ----------
__global__ void prep2_kernel(
  const float* __restrict__ lmw_i, const float* __restrict__ lmb_i, const float* __restrict__ lmb_h,
  const float* __restrict__ WemT, const float* __restrict__ be_m, const float* __restrict__ WcoT,
  ushort* __restrict__ Wbigfrag, float* __restrict__ bias_mgbig, ushort* __restrict__ Wofrag)
{
  int bid = blockIdx.x, tid = threadIdx.x;
  if (bid < 420) {                                 // Wbigfrag [10 kc][42 ft][64][8]
    int kc = bid / 42, ft = bid - kc*42;
    for (int e = tid; e < 512; e += 256) {
      int lane = e >> 3, j = e & 7;
      int n = ft*16 + (lane & 15);
      int k = kc*32 + (lane >> 4)*8 + j;
      float a = 0.f;
      if (n < 648) {
        const float* lw = lmw_i + (long)n*162;
        const float* wm = WemT + (long)k*192;
        for (int d = 0; d < 162; ++d) a += lw[d] * wm[d];
      }
      Wbigfrag[((long)bid*64 + lane)*8 + j] = (ushort)f2bf(a);
    }
  } else if (bid == 420) {                         // bias_mgbig [672]
    for (int n = tid; n < 672; n += 256) {
      float a = 0.f;
      if (n < 648) {
        a = lmb_i[n] + lmb_h[n];
        const float* lw = lmw_i + (long)n*162;
        for (int d = 0; d < 162; ++d) a += lw[d] * be_m[d];
      }
      bias_mgbig[n] = a;
    }
  } else {                                         // Wofrag [1][8][64][8]
    for (int i = tid; i < 4096; i += 256) {
      int ft = i >> 9; int lane = (i >> 3) & 63; int j = i & 7;
      int n = ft*16 + (lane & 15);
      int k = (lane >> 4)*8 + j;
      Wofrag[i] = (ushort)f2bf(WcoT[k*128 + n]);
    }
  }
}

// ---------- fused MFMA GCN: 1 wave = 1 site; 2 sites/block ----------
__global__ __launch_bounds__(128) void gcn2_kernel(
  const float* __restrict__ board,
  const ushort* __restrict__ adjfragG, const ushort* __restrict__ w1fragG,
  const ushort* __restrict__ g2fragG,
  const float* __restrict__ g1b, const float* __restrict__ g2b,
  ushort* __restrict__ bfout)   // bf16 [16000][192], cols 162..191 zero
{
  __shared__ ushort sX[2][3240];
  __shared__ ushort sF[2][3072];
  int tid = threadIdx.x; int w = tid >> 6; int lane = tid & 63;
  int col = lane & 15, grp = lane >> 4;
  long site = (long)blockIdx.x*2 + w;
  ushort* X = sX[w]; ushort* F = sF[w];

  short8 adjf[6][3];
  #pragma unroll
  for (int lt = 0; lt < 6; ++lt)
    #pragma unroll
    for (int kc = 0; kc < 3; ++kc)
      adjf[lt][kc] = *(const short8*)(adjfragG + ((lt*3+kc)*64 + lane)*8);
  short8 w1f0 = *(const short8*)(w1fragG + lane*8);
  short8 w1f1 = *(const short8*)(w1fragG + (64 + lane)*8);
  short8 g2f  = *(const short8*)(g2fragG + lane*8);
  float b1lo = g1b[col], b1hi = g1b[col + 16];
  float gb2  = (col < 2) ? g2b[col] : 0.f;
  f32x4 zero4 = {0.f, 0.f, 0.f, 0.f};
  short8 z8 = {0,0,0,0,0,0,0,0};

  const float* bp = board + site*2592;
  for (int idx = lane; idx < 648; idx += 64) {
    float4 v = *(const float4*)(bp + idx*4);
    uint lo = (f2bf(v.y)<<16) | f2bf(v.x);
    uint hi = (f2bf(v.w)<<16) | f2bf(v.z);
    int m = idx >> 3, q = idx & 7;
    *(uint2*)((char*)X + m*80 + q*8) = make_uint2(lo, hi);
  }
  if (grp >= 2) {
    *(short8*)((char*)F + (2*64 + lane)*16)     = z8;
    *(short8*)((char*)F + ((3+2)*64 + lane)*16) = z8;
  }

  #pragma unroll
  for (int lt = 0; lt < 6; ++lt) {
    short8 a = *(const short8*)((char*)X + (lt*16 + col)*80 + grp*16);
    f32x4 a0 = mfma16(a, w1f0, zero4);
    f32x4 a1 = mfma16(a, w1f1, zero4);
    #pragma unroll
    for (int r = 0; r < 4; ++r) {
      int m = lt*16 + grp*4 + r;
      if (m < 81) {
        int kc = m >> 5, g8 = (m & 31) >> 3, j = m & 7;
        ((ushort*)F)[ (kc*64 + g8*16 + col)*8 + j ]     = (ushort)f2bf(a0[r] + b1lo);
        ((ushort*)F)[ ((3+kc)*64 + g8*16 + col)*8 + j ] = (ushort)f2bf(a1[r] + b1hi);
      }
    }
  }

  short8 t1[2][3];
  #pragma unroll
  for (int ft = 0; ft < 2; ++ft)
    #pragma unroll
    for (int kc = 0; kc < 3; ++kc)
      t1[ft][kc] = *(const short8*)((char*)F + ((ft*3+kc)*64 + lane)*16);
  #pragma unroll
  for (int lt = 0; lt < 6; ++lt) {
    f32x4 c0 = zero4, c1 = zero4;
    #pragma unroll
    for (int kc = 0; kc < 3; ++kc) {
      c0 = mfma16(adjf[lt][kc], t1[0][kc], c0);
      c1 = mfma16(adjf[lt][kc], t1[1][kc], c1);
    }
    #pragma unroll
    for (int r = 0; r < 4; ++r) {
      int l = lt*16 + grp*4 + r;
      if (l < 81) {
        ((ushort*)X)[ l*40 + col ]      = (ushort)f2bf(fmaxf(c0[r], 0.f));
        ((ushort*)X)[ l*40 + col + 16 ] = (ushort)f2bf(fmaxf(c1[r], 0.f));
      }
    }
  }

  if (grp >= 2) *(short8*)((char*)F + (2*64 + lane)*16) = z8;

  #pragma unroll
  for (int lt = 0; lt < 6; ++lt) {
    short8 h = *(const short8*)((char*)X + (lt*16 + col)*80 + grp*16);
    f32x4 d = mfma16(h, g2f, zero4);
    if (col < 2) {
      #pragma unroll
      for (int r = 0; r < 4; ++r) {
        int m = lt*16 + grp*4 + r;
        if (m < 81) {
          int kc = m >> 5, g8 = (m & 31) >> 3, j = m & 7;
          ((ushort*)F)[ (kc*64 + g8*16 + col)*8 + j ] = (ushort)f2bf(d[r] + gb2);
        }
      }
    }
  }

  short8 t2[3];
  #pragma unroll
  for (int kc = 0; kc < 3; ++kc)
    t2[kc] = *(const short8*)((char*)F + (kc*64 + lane)*16);
  ushort* bfu = bfout + site*192;
  if (lane < 15) ((uint*)bfu)[81 + lane] = 0;   // zero pad cols 162..191
  #pragma unroll
  for (int lt = 0; lt < 6; ++lt) {
    f32x4 e = zero4;
    #pragma unroll
    for (int kc = 0; kc < 3; ++kc)
      e = mfma16(adjf[lt][kc], t2[kc], e);
    if (col < 2) {
      #pragma unroll
      for (int r = 0; r < 4; ++r) {
        int l = lt*16 + grp*4 + r;
        if (l < 81) bfu[l*2 + col] = (ushort)f2bf(fmaxf(e[r], 0.f));
      }
    }
  }
}

// ---------- MFMA GEMM ----------
template<int KC, int NT, int SRC_F32, int K, int NVALID, int OSTRIDE>
__global__ __launch_bounds__(512) void mgemm_kernel(
    const void* __restrict__ Ain, const ushort* __restrict__ Bfrag,
    const float* __restrict__ bias, ushort* __restrict__ out)
{
  constexpr int LSTRIDE = KC*64 + 16;
  __shared__ __align__(16) char sA[64 * LSTRIDE];
  int tid = threadIdx.x; int w = tid >> 6, lane = tid & 63;
  int col = lane & 15, grp = lane >> 4;
  long rowbase = (long)blockIdx.x * 64;

  if (SRC_F32) {
    constexpr int CH = K/8;
    const float* Af = (const float*)Ain + rowbase*K;
    for (int i = tid; i < 64*CH; i += 512) {
      int ch = i % CH, r = i / CH;
      const float* sp = Af + (long)r*K + ch*8;
      float4 v0 = *(const float4*)sp, v1 = *(const float4*)(sp+4);
      uint4 u;
      u.x = (f2bf(v0.y)<<16) | f2bf(v0.x);
      u.y = (f2bf(v0.w)<<16) | f2bf(v0.z);
      u.z = (f2bf(v1.y)<<16) | f2bf(v1.x);
      u.w = (f2bf(v1.w)<<16) | f2bf(v1.z);
      *(uint4*)(sA + r*LSTRIDE + ch*16) = u;
    }
  } else {
    constexpr int CH = KC*4;
    const ushort* Ab = (const ushort*)Ain + rowbase*(KC*32);
    for (int i = tid; i < 64*CH; i += 512) {
      int ch = i % CH, r = i / CH;
      *(uint4*)(sA + r*LSTRIDE + ch*16) = *(const uint4*)(Ab + (long)r*(KC*32) + ch*8);
    }
  }
  __syncthreads();

  constexpr int NG = NT/2;
  for (int ng = w; ng < NG; ng += 8) {
    int nt0 = ng*2;
    float bi0 = bias[nt0*16 + col], bi1 = bias[nt0*16 + 16 + col];
    f32x4 acc[4][2];
    #pragma unroll
    for (int mt=0;mt<4;++mt){
      acc[mt][0] = f32x4{bi0,bi0,bi0,bi0};
      acc[mt][1] = f32x4{bi1,bi1,bi1,bi1};
    }
    #pragma unroll 2
    for (int kc=0; kc<KC; ++kc) {
      const ushort* bp = Bfrag + (((long)kc*NT + nt0)*64 + lane)*8;
      short8 b0 = *(const short8*)bp;
      short8 b1 = *(const short8*)(bp + 512);
      #pragma unroll
      for (int mt=0; mt<4; ++mt) {
        short8 a = *(const short8*)(sA + (mt*16+col)*LSTRIDE + kc*64 + grp*16);
        acc[mt][0] = mfma16(a, b0, acc[mt][0]);
        acc[mt][1] = mfma16(a, b1, acc[mt][1]);
      }
    }
    #pragma unroll
    for (int mt=0;mt<4;++mt){
      #pragma unroll
      for (int nt=0;nt<2;++nt){
        int cg = nt0*16 + nt*16 + col;
        if (cg < NVALID) {
          #pragma unroll
          for (int r=0;r<4;++r){
            long row = rowbase + mt*16 + grp*4 + r;
            out[row*OSTRIDE + cg] = (ushort)f2bf(acc[mt][nt][r]);
          }
        }
      }
    }
  }
}

// ---------- LSTM recurrence: R3 design (banked best: 205 us) ----------
__global__ __launch_bounds__(1024) void lstm_kernel(
  const ushort* __restrict__ Gb, const ushort* __restrict__ Gm, const ushort* __restrict__ Go,
  const uint* __restrict__ whhB, const uint* __restrict__ whhM,
  const float* __restrict__ low_h,
  ushort* __restrict__ hsb, ushort* __restrict__ hsm, ushort* __restrict__ hso)
{
  int bid = blockIdx.x, tid = threadIdx.x;
  int f = bid / 80; int rr = bid - f*80;
  int pp = rr >> 4, jj = rr & 15;
  __shared__ __align__(16) uint s_h[96];
  __shared__ float s_part[4][784];
  if (f < 2) {
    const ushort* G  = f ? Gm : Gb;
    const uint* wh   = f ? whhM : whhB;
    ushort* hs       = f ? hsm : hsb;
    int kh = tid >> 8, g = tid & 255;
    uint w0[21], w1[21], w2[21];
    {
      const uint* wp = wh + (kh*768 + g)*21;
      #pragma unroll
      for (int q=0;q<21;++q){ w0[q]=wp[q]; w1[q]=wp[256*21+q]; w2[q]=wp[512*21+q]; }
    }
    if (tid < 96) s_h[tid] = 0u;
    float cc = 0.f;
    ushort pf0=0,pf1=0,pf2=0,pf3=0;
    if (tid < 162) {
      const ushort* Gr = G + (long)(pp*200 + jj)*648;
      pf0=Gr[tid]; pf1=Gr[162+tid]; pf2=Gr[324+tid]; pf3=Gr[486+tid];
    }
    __syncthreads();
    for (int t = 0; t < 200; ++t) {
      float a0=0.f, a1=0.f, a2=0.f;
      const uint* hb = s_h + kh*24;
      #pragma unroll
      for (int q4=0; q4<5; ++q4) {
        uint4 hv = *(const uint4*)(hb + q4*4);
        int q = q4*4;
        a0=fdot2(hv.x,w0[q  ],a0); a1=fdot2(hv.x,w1[q  ],a1); a2=fdot2(hv.x,w2[q  ],a2);
        a0=fdot2(hv.y,w0[q+1],a0); a1=fdot2(hv.y,w1[q+1],a1); a2=fdot2(hv.y,w2[q+1],a2);
        a0=fdot2(hv.z,w0[q+2],a0); a1=fdot2(hv.z,w1[q+2],a1); a2=fdot2(hv.z,w2[q+2],a2);
        a0=fdot2(hv.w,w0[q+3],a0); a1=fdot2(hv.w,w1[q+3],a1); a2=fdot2(hv.w,w2[q+3],a2);
      }
      { uint hv = hb[20];
        a0=fdot2(hv,w0[20],a0); a1=fdot2(hv,w1[20],a1); a2=fdot2(hv,w2[20],a2); }
      s_part[kh][g      ] = a0;
      s_part[kh][g + 256] = a1;
      s_part[kh][g + 512] = a2;
      __syncthreads();
      if (tid < 162) {
        float gi = s_part[0][tid    ]+s_part[1][tid    ]+s_part[2][tid    ]+s_part[3][tid    ] + bf2f(pf0);
        float gf = s_part[0][162+tid]+s_part[1][162+tid]+s_part[2][162+tid]+s_part[3][162+tid] + bf2f(pf1);
        float gg = s_part[0][324+tid]+s_part[1][324+tid]+s_part[2][324+tid]+s_part[3][324+tid] + bf2f(pf2);
        float go = s_part[0][486+tid]+s_part[1][486+tid]+s_part[2][486+tid]+s_part[3][486+tid] + bf2f(pf3);
        if (t+1 < 200) {
          int m2 = (t+1)*16 + jj; int bb = m2/200; int ss = m2 - bb*200;
          const ushort* Gr = G + (long)((bb*5+pp)*200 + ss)*648;
          pf0=Gr[tid]; pf1=Gr[162+tid]; pf2=Gr[324+tid]; pf3=Gr[486+tid];
        }
        cc = sigm(gf)*cc + sigm(gi)*tanh_(gg);
        float h = sigm(go)*tanh_(cc);
        int p = tid >> 1; int khw = p/21; int qw = p - khw*21;
        ((ushort*)s_h)[(khw*24+qw)*2 + (tid&1)] = f16bits(h);
        hs[(long)(t*80+rr)*162 + tid] = (ushort)f2bf(h);
      }
      __syncthreads();
    }
  } else {
    // order LSTM: H=32, 128 gates
    float w[32];
    if (tid < 128) {
      #pragma unroll
      for (int q=0;q<32;++q) w[q] = low_h[tid*32+q];
    }
    float* s_ho = (float*)s_h;          // 32 floats
    float* s_po = &s_part[0][0];        // 128 floats
    if (tid < 32) s_ho[tid] = 0.f;
    float cc=0.f; ushort pf0=0,pf1=0,pf2=0,pf3=0;
    if (tid < 32) {
      const ushort* Gr = Go + (long)(pp*200 + jj)*128;
      pf0=Gr[tid]; pf1=Gr[32+tid]; pf2=Gr[64+tid]; pf3=Gr[96+tid];
    }
    __syncthreads();
    for (int t=0; t<200; ++t) {
      if (tid < 128) {
        float a = 0.f;
        const float4* h4 = (const float4*)s_ho;
        #pragma unroll
        for (int q4=0;q4<8;++q4) {
          float4 hv = h4[q4];
          a += hv.x*w[q4*4] + hv.y*w[q4*4+1] + hv.z*w[q4*4+2] + hv.w*w[q4*4+3];
        }
        s_po[tid] = a;
      }
      __syncthreads();
      if (tid < 32) {
        float gi = s_po[tid]      + bf2f(pf0);
        float gf = s_po[32 + tid] + bf2f(pf1);
        float gg = s_po[64 + tid] + bf2f(pf2);
        float go = s_po[96 + tid] + bf2f(pf3);
        if (t+1 < 200) {
          int m2 = (t+1)*16 + jj; int bb = m2/200; int ss = m2 - bb*200;
          const ushort* Gr = Go + (long)((bb*5+pp)*200 + ss)*128;
          pf0=Gr[tid]; pf1=Gr[32+tid]; pf2=Gr[64+tid]; pf3=Gr[96+tid];
        }
        cc = sigm(gf)*cc + sigm(gi)*tanh_(gg);
        float h = sigm(go)*tanh_(cc);
        s_ho[tid] = h;
        hso[(long)(t*80+rr)*32 + tid] = (ushort)f2bf(h);
      }
      __syncthreads();
    }
  }
}

// ---------- final FC: K split 25-ways (t-groups of 8) for occupancy ----------
__global__ __launch_bounds__(256) void fc_kernel(
  const ushort* __restrict__ hsb, const ushort* __restrict__ hso, const ushort* __restrict__ hsm,
  const ushort* __restrict__ fb3wT, const ushort* __restrict__ fo3wT, const ushort* __restrict__ fm3wT,
  const float* __restrict__ fb3b, const float* __restrict__ fo3b, const float* __restrict__ fm3b,
  float* __restrict__ out)
{
  __shared__ float s_hsum[8*162];
  int bid = blockIdx.x, tid = threadIdx.x;
  int f = bid / 400;
  int rem = bid - f*400;
  int j = rem / 25, tg = rem - (rem/25)*25;
  int H = (f==1) ? 32 : 162;
  const ushort* hs = (f==0) ? hsb : (f==1) ? hso : hsm;
  const ushort* WT = (f==0) ? fb3wT : (f==1) ? fo3wT : fm3wT;
  int KL = 8*H;
  for (int idx = tid; idx < KL; idx += 256) {
    int tl = idx / H; int h = idx - tl*H;
    int t = tg*8 + tl;
    long base = (long)(t*80 + j)*H + h;
    float s = 0.f;
    #pragma unroll
    for (int p=0;p<5;++p) s += bf2f(hs[base + (long)p*16*H]);
    s_hsum[idx] = s;
  }
  __syncthreads();
  int o0 = (tid & 15)*4, kq = tid >> 4;
  float a0=0.f,a1=0.f,a2=0.f,a3=0.f;
  long kgbase = (long)tg*8*H;
  for (int kk = kq; kk < KL; kk += 16) {
    float hv = s_hsum[kk];
    const uint* wr = (const uint*)(WT + (kgbase + kk)*64 + o0);
    uint u0 = wr[0], u1 = wr[1];
    a0 += hv*bflo(u0); a1 += hv*bfhi(u0); a2 += hv*bflo(u1); a3 += hv*bfhi(u1);
  }
  __syncthreads();
  float* s_red = s_hsum;
  s_red[kq*64 + o0] = a0; s_red[kq*64 + o0 + 1] = a1;
  s_red[kq*64 + o0 + 2] = a2; s_red[kq*64 + o0 + 3] = a3;
  __syncthreads();
  if (tid < 64) {
    float v = 0.f;
    #pragma unroll
    for (int q=0;q<16;++q) v += s_red[q*64 + tid];
    if (f==0 && tg==0) v += 5.f*(fb3b[tid] + fo3b[tid] + fm3b[tid]);
    atomicAdd(out + j*64 + tid, v);
  }
}

// ---------- launch ----------
extern "C" void kernel_launch(void* const* d_in, const int* in_sizes, int n_in,
                              void* d_out, int out_size, void* d_ws, size_t ws_size,
                              hipStream_t stream)
{
  const float* board = (const float*)d_in[0];
  const float* order = (const float*)d_in[1];
  const float* msg   = (const float*)d_in[2];
  const float* adj   = (const float*)d_in[3];
  const float* g1w = (const float*)d_in[4];  const float* g1b = (const float*)d_in[5];
  const float* g2w = (const float*)d_in[6];  const float* g2b = (const float*)d_in[7];
  const float* lbw_i = (const float*)d_in[8];  const float* lbw_h = (const float*)d_in[9];
  const float* lbb_i = (const float*)d_in[10]; const float* lbb_h = (const float*)d_in[11];
  const float* fb3w = (const float*)d_in[12];  const float* fb3b = (const float*)d_in[13];
  const float* fo1w = (const float*)d_in[14];  const float* fo1b = (const float*)d_in[15];
  const float* fo2w = (const float*)d_in[16];  const float* fo2b = (const float*)d_in[17];
  const float* low_i = (const float*)d_in[18]; const float* low_h = (const float*)d_in[19];
  const float* lob_i = (const float*)d_in[20]; const float* lob_h = (const float*)d_in[21];
  const float* fo3w = (const float*)d_in[22];  const float* fo3b = (const float*)d_in[23];
  const float* fm1w = (const float*)d_in[24];  const float* fm1b = (const float*)d_in[25];
  const float* fm2w = (const float*)d_in[26];  const float* fm2b = (const float*)d_in[27];
  const float* lmw_i = (const float*)d_in[28]; const float* lmw_h = (const float*)d_in[29];
  const float* lmb_i = (const float*)d_in[30]; const float* lmb_h = (const float*)d_in[31];
  const float* fm3w = (const float*)d_in[32];  const float* fm3b = (const float*)d_in[33];

  char* wsb = (char*)d_ws;
  size_t off = 0;
  auto alloc = [&](size_t bytes)->char* { char* p = wsb + off; off = (off + bytes + 255) & ~(size_t)255; return p; };
  float* bias_bg   = (float*)alloc(672*4);
  float* WemT      = (float*)alloc((size_t)320*192*4);
  float* be_m      = (float*)alloc(192*4);
  float* WcoT      = (float*)alloc((size_t)32*128*4);
  float* bias_og   = (float*)alloc(128*4);
  float* bias_mgbig= (float*)alloc(672*4);
  ushort* fb3wT  = (ushort*)alloc((size_t)2073600*2);
  ushort* fo3wT  = (ushort*)alloc((size_t)409600*2);
  ushort* fm3wT  = (ushort*)alloc((size_t)2073600*2);
  uint* whhB     = (uint*)alloc((size_t)64512*4);
  uint* whhM     = (uint*)alloc((size_t)64512*4);
  ushort* adjfragG = (ushort*)alloc((size_t)18*64*8*2);
  ushort* w1fragG  = (ushort*)alloc((size_t)2*64*8*2);
  ushort* g2fragG  = (ushort*)alloc((size_t)64*8*2);
  ushort* Gbfrag   = (ushort*)alloc((size_t)6*42*512*2);
  ushort* Wbigfrag = (ushort*)alloc((size_t)10*42*512*2);
  ushort* Wofrag   = (ushort*)alloc((size_t)4096*2);
  ushort* bf     = (ushort*)alloc((size_t)16000*192*2);
  ushort* Gb     = (ushort*)alloc((size_t)16000*648*2);
  ushort* Gm     = (ushort*)alloc((size_t)16000*648*2);
  ushort* Go     = (ushort*)alloc((size_t)16000*128*2);
  ushort* hsb    = (ushort*)alloc((size_t)16000*162*2);
  ushort* hsm    = (ushort*)alloc((size_t)16000*162*2);
  ushort* hso    = (ushort*)alloc((size_t)16000*32*2);
  if (off > ws_size) return;

  prep_kernel<<<755, 256, 0, stream>>>(adj, g1w, g2w, lbw_i, lbw_h, lbb_i, lbb_h,
      lmw_h, fo1w, fo1b, fo2w, fo2b, low_i, lob_i, lob_h,
      fm1w, fm1b, fm2w, fm2b, fb3w, fo3w, fm3w,
      bias_bg, WemT, be_m, WcoT, bias_og,
      fb3wT, fo3wT, fm3wT, whhB, whhM, adjfragG, w1fragG, g2fragG, Gbfrag);
  prep2_kernel<<<422, 256, 0, stream>>>(lmw_i, lmb_i, lmb_h, WemT, be_m, WcoT,
      Wbigfrag, bias_mgbig, Wofrag);
  gcn2_kernel<<<8000, 128, 0, stream>>>(board, adjfragG, w1fragG, g2fragG, g1b, g2b, bf);
  mgemm_kernel<6,42,0,192,648,648><<<250, 512, 0, stream>>>(bf, Gbfrag, bias_bg, Gb);
  mgemm_kernel<10,42,1,320,648,648><<<250, 512, 0, stream>>>(msg, Wbigfrag, bias_mgbig, Gm);
  mgemm_kernel<1,8,1,32,128,128><<<250, 512, 0, stream>>>(order, Wofrag, bias_og, Go);
  lstm_kernel<<<240, 1024, 0, stream>>>(Gb, Gm, Go, whhB, whhM, low_h, hsb, hsm, hso);
  hipMemsetAsync(d_out, 0, (size_t)out_size*sizeof(float), stream);
  fc_kernel<<<1200, 256, 0, stream>>>(hsb, hso, hsm,
      fb3wT, fo3wT, fm3wT, fb3b, fo3b, fm3b, (float*)d_out);
}